// Round 2
// baseline (710.741 us; speedup 1.0000x reference)
//
#include <hip/hip_runtime.h>
#include <math.h>

#define Vv   50000
#define EMB  128
#define Hh   256
#define TKk  400
#define Bb   128
#define OOVn 10
#define N2n  512
#define VOo  50010   // V + OOV

__device__ __forceinline__ float sigf(float x) { return 1.f / (1.f + __expf(-x)); }
__device__ __forceinline__ float tanh_fast(float x) {
    x = fminf(15.f, fmaxf(-15.f, x));
    float e = __expf(2.f * x);
    return (e - 1.f) / (e + 1.f);
}
__device__ __forceinline__ float wave_red(float v) {
    #pragma unroll
    for (int o = 32; o; o >>= 1) v += __shfl_down(v, o);
    return v;
}

// x[b,j] = concat(c_t_1, emb[y[b]]) . Wx[j,:] + bx[j] — one wave per j
__global__ __launch_bounds__(64) void k_x(
    const int* __restrict__ y, const float* __restrict__ ct1,
    const float* __restrict__ emb, const float* __restrict__ Wx,
    const float* __restrict__ bx, float* __restrict__ xw)
{
    int j = blockIdx.x, l = threadIdx.x;
    float w[10];
    #pragma unroll
    for (int i = 0; i < 10; i++) w[i] = Wx[(size_t)j * 640 + l + 64 * i];
    float bj = bx[j];
    #pragma unroll 2
    for (int b = 0; b < Bb; b++) {
        int yy = y[b];
        float a = 0.f;
        #pragma unroll
        for (int i = 0; i < 8; i++) a += ct1[b * 512 + l + 64 * i] * w[i];
        #pragma unroll
        for (int i = 0; i < 2; i++) a += emb[(size_t)yy * 128 + l + 64 * i] * w[8 + i];
        a = wave_red(a);
        if (l == 0) xw[b * 128 + j] = a + bj;
    }
}

// gates[b,j] = x·wih[j] + h0·whh[j] + biases — one wave per j
__global__ __launch_bounds__(64) void k_gates(
    const float* __restrict__ xw, const float* __restrict__ h0,
    const float* __restrict__ wih, const float* __restrict__ bih,
    const float* __restrict__ whh, const float* __restrict__ bhh,
    float* __restrict__ gates)
{
    int j = blockIdx.x, l = threadIdx.x;
    float wi0 = wih[(size_t)j * 128 + l];
    float wi1 = wih[(size_t)j * 128 + l + 64];
    float wh[4];
    #pragma unroll
    for (int i = 0; i < 4; i++) wh[i] = whh[(size_t)j * 256 + l + 64 * i];
    float bj = bih[j] + bhh[j];
    #pragma unroll 2
    for (int b = 0; b < Bb; b++) {
        float a = xw[b * 128 + l] * wi0 + xw[b * 128 + l + 64] * wi1;
        #pragma unroll
        for (int i = 0; i < 4; i++) a += h0[b * 256 + l + 64 * i] * wh[i];
        a = wave_red(a);
        if (l == 0) gates[b * 1024 + j] = a + bj;
    }
}

// LSTM pointwise (torch gate order i,f,g,o)
__global__ __launch_bounds__(256) void k_lstm(
    const float* __restrict__ gates, const float* __restrict__ c0,
    float* __restrict__ h1o, float* __restrict__ c1o)
{
    int b = blockIdx.x, n = threadIdx.x;
    float ig = sigf(gates[b * 1024 + n]);
    float fg = sigf(gates[b * 1024 + n + 256]);
    float gg = tanh_fast(gates[b * 1024 + n + 512]);
    float og = sigf(gates[b * 1024 + n + 768]);
    float c1 = fg * c0[b * 256 + n] + ig * gg;
    float h1 = og * tanh_fast(c1);
    h1o[b * 256 + n] = h1;
    c1o[b * 256 + n] = c1;
}

// dec_fea[b,j] = [h1,c1]·Wp[j,:] + bp[j] — one wave per j
__global__ __launch_bounds__(64) void k_dec_fea(
    const float* __restrict__ h1, const float* __restrict__ c1,
    const float* __restrict__ Wp, const float* __restrict__ bp,
    float* __restrict__ dfw)
{
    int j = blockIdx.x, l = threadIdx.x;
    float w[8];
    #pragma unroll
    for (int i = 0; i < 8; i++) w[i] = Wp[(size_t)j * 512 + l + 64 * i];
    float bj = bp[j];
    #pragma unroll 2
    for (int b = 0; b < Bb; b++) {
        float a = 0.f;
        #pragma unroll
        for (int i = 0; i < 4; i++) a += h1[b * 256 + l + 64 * i] * w[i];
        #pragma unroll
        for (int i = 0; i < 4; i++) a += c1[b * 256 + l + 64 * i] * w[4 + i];
        a = wave_red(a);
        if (l == 0) dfw[b * 512 + j] = a + bj;
    }
}

// scores[b,t] — one wave per (b,t)
__global__ __launch_bounds__(256) void k_scores(
    const float* __restrict__ ef, const float* __restrict__ df,
    const float* __restrict__ cov, const float* __restrict__ Wc,
    const float* __restrict__ vw, float* __restrict__ sc)
{
    int w = threadIdx.x >> 6, lane = threadIdx.x & 63;
    int idx = blockIdx.x * 4 + w;
    int b = idx / TKk;
    const float* e = ef + (size_t)idx * N2n;
    const float* d = df + (size_t)b * N2n;
    float cv = cov[idx];
    float acc = 0.f;
    #pragma unroll
    for (int i = 0; i < 2; i++) {
        int n0 = lane * 4 + i * 256;
        float4 ev = *(const float4*)(e + n0);
        float4 dv = *(const float4*)(d + n0);
        float4 wc = *(const float4*)(Wc + n0);
        float4 vv = *(const float4*)(vw + n0);
        acc += tanh_fast(ev.x + dv.x + cv * wc.x) * vv.x;
        acc += tanh_fast(ev.y + dv.y + cv * wc.y) * vv.y;
        acc += tanh_fast(ev.z + dv.z + cv * wc.z) * vv.z;
        acc += tanh_fast(ev.w + dv.w + cv * wc.w) * vv.w;
    }
    acc = wave_red(acc);
    if (lane == 0) sc[idx] = acc;
}

// masked softmax over TK + coverage update — one block per b
__global__ __launch_bounds__(512) void k_attn(
    const float* __restrict__ sc, const float* __restrict__ mask,
    const float* __restrict__ covi, float* __restrict__ attn,
    float* __restrict__ covo)
{
    int b = blockIdx.x, tid = threadIdx.x;
    __shared__ float red[8];
    __shared__ float bc;
    float s = (tid < TKk) ? sc[b * TKk + tid] : -3.4e38f;
    float m = s;
    for (int off = 32; off; off >>= 1) m = fmaxf(m, __shfl_down(m, off));
    if ((tid & 63) == 0) red[tid >> 6] = m;
    __syncthreads();
    if (tid == 0) {
        float t = red[0];
        for (int i = 1; i < 8; i++) t = fmaxf(t, red[i]);
        bc = t;
    }
    __syncthreads();
    float M = bc;
    float w = (tid < TKk) ? __expf(s - M) * mask[b * TKk + tid] : 0.f;
    float ss = wave_red(w);
    if ((tid & 63) == 0) red[tid >> 6] = ss;
    __syncthreads();
    if (tid == 0) {
        float t = 0.f;
        for (int i = 0; i < 8; i++) t += red[i];
        bc = t;
    }
    __syncthreads();
    float a = w / bc;
    if (tid < TKk) {
        attn[b * TKk + tid] = a;
        covo[b * TKk + tid] = covi[b * TKk + tid] + a;
    }
}

// context partials over 100-key chunks
__global__ __launch_bounds__(512) void k_ctx(
    const float* __restrict__ attn, const float* __restrict__ eo,
    float* __restrict__ part)
{
    int bs = blockIdx.x;
    int b = bs >> 2, s = bs & 3;
    int n = threadIdx.x;
    __shared__ float av[100];
    if (n < 100) av[n] = attn[b * TKk + s * 100 + n];
    __syncthreads();
    const float* p = eo + ((size_t)b * TKk + s * 100) * N2n + n;
    float acc = 0.f;
    #pragma unroll 4
    for (int t = 0; t < 100; t++) acc += av[t] * p[(size_t)t * N2n];
    part[(size_t)bs * N2n + n] = acc;
}

// c_t reduce + p_gen — one block per b
__global__ __launch_bounds__(512) void k_ctred(
    const float* __restrict__ part, const float* __restrict__ h1,
    const float* __restrict__ c1, const float* __restrict__ xw,
    const float* __restrict__ Wpg, const float* __restrict__ bpg,
    float* __restrict__ cto, float* __restrict__ pgo)
{
    int b = blockIdx.x, tid = threadIdx.x;
    __shared__ float ct[N2n];
    __shared__ float red[8];
    float a = part[((size_t)b * 4 + 0) * N2n + tid]
            + part[((size_t)b * 4 + 1) * N2n + tid]
            + part[((size_t)b * 4 + 2) * N2n + tid]
            + part[((size_t)b * 4 + 3) * N2n + tid];
    ct[tid] = a;
    cto[b * N2n + tid] = a;
    __syncthreads();

    float pa = 0.f;
    for (int k = tid; k < 1152; k += 512) {
        float vv = (k < 512) ? ct[k] : (k < 768) ? h1[b * 256 + k - 512]
                 : (k < 1024) ? c1[b * 256 + k - 768] : xw[b * 128 + k - 1024];
        pa += vv * Wpg[k];
    }
    pa = wave_red(pa);
    if ((tid & 63) == 0) red[tid >> 6] = pa;
    __syncthreads();
    if (tid == 0) {
        float t = 0.f;
        for (int i = 0; i < 8; i++) t += red[i];
        pgo[b] = sigf(t + bpg[0]);
    }
}

// output[b,j] = [h1,c_t]·W1[j,:] + b1[j] — one wave per j
__global__ __launch_bounds__(64) void k_out(
    const float* __restrict__ h1, const float* __restrict__ cto,
    const float* __restrict__ W1, const float* __restrict__ b1,
    float* __restrict__ ov)
{
    int j = blockIdx.x, l = threadIdx.x;
    float w[12];
    #pragma unroll
    for (int i = 0; i < 12; i++) w[i] = W1[(size_t)j * 768 + l + 64 * i];
    float bj = b1[j];
    #pragma unroll 2
    for (int b = 0; b < Bb; b++) {
        float a = 0.f;
        #pragma unroll
        for (int i = 0; i < 4; i++) a += h1[b * 256 + l + 64 * i] * w[i];
        #pragma unroll
        for (int i = 0; i < 8; i++) a += cto[b * 512 + l + 64 * i] * w[4 + i];
        a = wave_red(a);
        if (l == 0) ov[b * 256 + j] = a + bj;
    }
}

// vocab GEMM: tile M=128 x N=64, Kc=16, micro 8x4
__global__ __launch_bounds__(256) void k_gemm(
    const float* __restrict__ Aw, const float* __restrict__ W2,
    const float* __restrict__ b2, float* __restrict__ fd)
{
    __shared__ float As[16 * 128];   // [k][m]
    __shared__ float Bs[16 * 64];    // [k][n]
    int tid = threadIdx.x;
    int tx = tid & 15;        // n = tx*4
    int ty = tid >> 4;        // m = ty*8
    int v0 = blockIdx.x * 64;
    int am = tid & 127, ah = tid >> 7;
    int bn = tid & 63,  bq = tid >> 6;

    float acc[8][4] = {};

    for (int kt = 0; kt < 256; kt += 16) {
        float4 a0 = *(const float4*)(Aw + (size_t)am * 256 + kt + ah * 8);
        float4 a1 = *(const float4*)(Aw + (size_t)am * 256 + kt + ah * 8 + 4);
        int vv = v0 + bn;
        float4 bv = make_float4(0.f, 0.f, 0.f, 0.f);
        if (vv < Vv) bv = *(const float4*)(W2 + (size_t)vv * 256 + kt + bq * 4);
        __syncthreads();
        As[(ah * 8 + 0) * 128 + am] = a0.x; As[(ah * 8 + 1) * 128 + am] = a0.y;
        As[(ah * 8 + 2) * 128 + am] = a0.z; As[(ah * 8 + 3) * 128 + am] = a0.w;
        As[(ah * 8 + 4) * 128 + am] = a1.x; As[(ah * 8 + 5) * 128 + am] = a1.y;
        As[(ah * 8 + 6) * 128 + am] = a1.z; As[(ah * 8 + 7) * 128 + am] = a1.w;
        Bs[(bq * 4 + 0) * 64 + bn] = bv.x; Bs[(bq * 4 + 1) * 64 + bn] = bv.y;
        Bs[(bq * 4 + 2) * 64 + bn] = bv.z; Bs[(bq * 4 + 3) * 64 + bn] = bv.w;
        __syncthreads();
        #pragma unroll
        for (int k = 0; k < 16; k++) {
            float4 A0 = *(const float4*)&As[k * 128 + ty * 8];
            float4 A1 = *(const float4*)&As[k * 128 + ty * 8 + 4];
            float4 Bv = *(const float4*)&Bs[k * 64 + tx * 4];
            float amv[8] = {A0.x, A0.y, A0.z, A0.w, A1.x, A1.y, A1.z, A1.w};
            float bnv[4] = {Bv.x, Bv.y, Bv.z, Bv.w};
            #pragma unroll
            for (int i = 0; i < 8; i++)
                #pragma unroll
                for (int j = 0; j < 4; j++) acc[i][j] += amv[i] * bnv[j];
        }
    }
    int v = v0 + tx * 4;
    if (v < Vv) {
        float4 bb = *(const float4*)(b2 + v);
        #pragma unroll
        for (int i = 0; i < 8; i++) {
            int m = ty * 8 + i;
            float* p = fd + (size_t)m * VOo + v;
            // row stride 50010 breaks 16B alignment for odd m -> float2 stores
            *(float2*)(p)     = make_float2(acc[i][0] + bb.x, acc[i][1] + bb.y);
            *(float2*)(p + 2) = make_float2(acc[i][2] + bb.z, acc[i][3] + bb.w);
        }
    }
}

// vocab softmax partials per (b, quarter)
__global__ __launch_bounds__(256) void k_vs1(
    const float* __restrict__ fd, float* __restrict__ pm, float* __restrict__ ps)
{
    int blk = blockIdx.x, b = blk >> 2, c = blk & 3;
    int tid = threadIdx.x;
    const float* l = fd + (size_t)b * VOo + c * 12500;
    __shared__ float red[4];
    __shared__ float bc;
    float m = -3.4e38f;
    for (int v = tid; v < 12500; v += 256) m = fmaxf(m, l[v]);
    for (int off = 32; off; off >>= 1) m = fmaxf(m, __shfl_down(m, off));
    if ((tid & 63) == 0) red[tid >> 6] = m;
    __syncthreads();
    if (tid == 0) bc = fmaxf(fmaxf(red[0], red[1]), fmaxf(red[2], red[3]));
    __syncthreads();
    float M = bc;
    float s = 0.f;
    for (int v = tid; v < 12500; v += 256) s += __expf(l[v] - M);
    s = wave_red(s);
    if ((tid & 63) == 0) red[tid >> 6] = s;
    __syncthreads();
    if (tid == 0) { pm[blk] = M; ps[blk] = red[0] + red[1] + red[2] + red[3]; }
}

// combine + normalize in place + p_gen scale + OOV tail
__global__ __launch_bounds__(256) void k_vs3(
    const float* __restrict__ pm, const float* __restrict__ ps,
    const float* __restrict__ pgen, const float* __restrict__ extra,
    float* __restrict__ fd)
{
    int blk = blockIdx.x, b = blk >> 2, c = blk & 3;
    float m0 = pm[b * 4], m1 = pm[b * 4 + 1], m2 = pm[b * 4 + 2], m3 = pm[b * 4 + 3];
    float M = fmaxf(fmaxf(m0, m1), fmaxf(m2, m3));
    float S = ps[b * 4] * __expf(m0 - M) + ps[b * 4 + 1] * __expf(m1 - M)
            + ps[b * 4 + 2] * __expf(m2 - M) + ps[b * 4 + 3] * __expf(m3 - M);
    float scale = pgen[b] / S;
    float* l = fd + (size_t)b * VOo + c * 12500;
    for (int v = threadIdx.x; v < 12500; v += 256) l[v] = __expf(l[v] - M) * scale;
    if (c == 0 && threadIdx.x < OOVn)
        fd[(size_t)b * VOo + Vv + threadIdx.x] = extra[b * OOVn + threadIdx.x];
}

// pointer scatter-add
__global__ __launch_bounds__(256) void k_scatter(
    const int* __restrict__ ebev, const float* __restrict__ attn,
    const float* __restrict__ pgen, float* __restrict__ fd)
{
    int gid = blockIdx.x * 256 + threadIdx.x;
    if (gid >= Bb * TKk) return;
    int b = gid / TKk;
    float w = (1.f - pgen[b]) * attn[gid];
    atomicAdd(fd + (size_t)b * VOo + ebev[gid], w);
}

extern "C" void kernel_launch(void* const* d_in, const int* in_sizes, int n_in,
                              void* d_out, int out_size, void* d_ws, size_t ws_size,
                              hipStream_t stream)
{
    (void)in_sizes; (void)n_in; (void)out_size; (void)ws_size;

    const int*   y    = (const int*)d_in[0];
    const float* h0   = (const float*)d_in[1];
    const float* c0   = (const float*)d_in[2];
    const float* eo   = (const float*)d_in[3];
    const float* ef   = (const float*)d_in[4];
    const float* mask = (const float*)d_in[5];
    const float* ct1  = (const float*)d_in[6];
    const float* xz   = (const float*)d_in[7];
    const int*   ebev = (const int*)d_in[8];
    const float* cov  = (const float*)d_in[9];
    const float* emb  = (const float*)d_in[11];
    const float* Wx   = (const float*)d_in[12];
    const float* bx   = (const float*)d_in[13];
    const float* wih  = (const float*)d_in[14];
    const float* bih  = (const float*)d_in[15];
    const float* whh  = (const float*)d_in[16];
    const float* bhh  = (const float*)d_in[17];
    const float* Wp   = (const float*)d_in[18];
    const float* bp   = (const float*)d_in[19];
    const float* vw   = (const float*)d_in[20];
    const float* Wc   = (const float*)d_in[21];
    const float* Wpg  = (const float*)d_in[22];
    const float* bpg  = (const float*)d_in[23];
    const float* W1   = (const float*)d_in[24];
    const float* b1   = (const float*)d_in[25];
    const float* W2   = (const float*)d_in[26];
    const float* b2   = (const float*)d_in[27];

    float* out   = (float*)d_out;
    float* fd    = out;                              // [B, VO]
    float* h1o   = out + (size_t)Bb * VOo;           // [B, H]
    float* c1o   = h1o + (size_t)Bb * Hh;            // [B, H]
    float* cto   = c1o + (size_t)Bb * Hh;            // [B, N2]
    float* attno = cto + (size_t)Bb * N2n;           // [B, TK]
    float* pgo   = attno + (size_t)Bb * TKk;         // [B]
    float* covo  = pgo + Bb;                         // [B, TK]

    float* ws  = (float*)d_ws;
    float* xw  = ws;                                 // [B,128]
    float* dfw = xw + (size_t)Bb * EMB;              // [B,512]
    float* scw = dfw + (size_t)Bb * N2n;             // [B,400]
    float* prt = scw + (size_t)Bb * TKk;             // [B,4,512]
    float* gsw = prt + (size_t)Bb * 4 * N2n;         // [B,1024]
    float* ovw = gsw + (size_t)Bb * 1024;            // [B,256]
    float* pmw = ovw + (size_t)Bb * Hh;              // [512]
    float* psw = pmw + 512;                          // [512]

    k_x<<<128, 64, 0, stream>>>(y, ct1, emb, Wx, bx, xw);
    k_gates<<<1024, 64, 0, stream>>>(xw, h0, wih, bih, whh, bhh, gsw);
    k_lstm<<<128, 256, 0, stream>>>(gsw, c0, h1o, c1o);
    k_dec_fea<<<512, 64, 0, stream>>>(h1o, c1o, Wp, bp, dfw);
    k_scores<<<Bb * TKk / 4, 256, 0, stream>>>(ef, dfw, cov, Wc, vw, scw);
    k_attn<<<Bb, 512, 0, stream>>>(scw, mask, cov, attno, covo);
    k_ctx<<<Bb * 4, 512, 0, stream>>>(attno, eo, prt);
    k_ctred<<<Bb, 512, 0, stream>>>(prt, h1o, c1o, xw, Wpg, bpg, cto, pgo);
    k_out<<<256, 64, 0, stream>>>(h1o, cto, W1, b1, ovw);
    k_gemm<<<(Vv + 63) / 64, 256, 0, stream>>>(ovw, W2, b2, fd);
    k_vs1<<<512, 256, 0, stream>>>(fd, pmw, psw);
    k_vs3<<<512, 256, 0, stream>>>(pmw, psw, pgo, xz, fd);
    k_scatter<<<(Bb * TKk + 255) / 256, 256, 0, stream>>>(ebev, attno, pgo, fd);
}

// Round 3
// 449.948 us; speedup vs baseline: 1.5796x; 1.5796x over previous
//
#include <hip/hip_runtime.h>
#include <math.h>

#define Vv   50000
#define EMB  128
#define Hh   256
#define TKk  400
#define Bb   128
#define OOVn 10
#define N2n  512
#define VOo  50010   // V + OOV

__device__ __forceinline__ float sigf(float x) { return 1.f / (1.f + __expf(-x)); }
__device__ __forceinline__ float tanh_fast(float x) {
    x = fminf(15.f, fmaxf(-15.f, x));
    float e = __expf(2.f * x);
    return (e - 1.f) / (e + 1.f);
}
__device__ __forceinline__ float wave_red(float v) {
    #pragma unroll
    for (int o = 32; o; o >>= 1) v += __shfl_down(v, o);
    return v;
}

// ---------------------------------------------------------------------------
// K1: x[b,j] = concat(c_t_1, emb[y[b]]) . Wx[j,:] + bx[j]
// wave per (j, 4-b group). grid (J/4, B/4), block 256 (4 waves)
// ---------------------------------------------------------------------------
__global__ __launch_bounds__(256) void k_x(
    const int* __restrict__ y, const float* __restrict__ ct1,
    const float* __restrict__ emb, const float* __restrict__ Wx,
    const float* __restrict__ bx, float* __restrict__ xw)
{
    int l = threadIdx.x & 63;
    int j = blockIdx.x * 4 + (threadIdx.x >> 6);
    int b0 = blockIdx.y * 4;
    float w[10];
    #pragma unroll
    for (int i = 0; i < 10; i++) w[i] = Wx[(size_t)j * 640 + l + 64 * i];
    float bj = bx[j];
    #pragma unroll
    for (int bi = 0; bi < 4; bi++) {
        int b = b0 + bi;
        int yy = y[b];
        float a = 0.f;
        #pragma unroll
        for (int i = 0; i < 8; i++) a += ct1[b * 512 + l + 64 * i] * w[i];
        #pragma unroll
        for (int i = 0; i < 2; i++) a += emb[(size_t)yy * 128 + l + 64 * i] * w[8 + i];
        a = wave_red(a);
        if (l == 0) xw[b * 128 + j] = a + bj;
    }
}

// ---------------------------------------------------------------------------
// K2: gates + LSTM fused. block = 4 waves; wave g computes gate j = g*256+n
// for 4 b's; LDS combine; threads 0..3 apply the cell and write h1,c1.
// grid (n=256, B/4=32)
// ---------------------------------------------------------------------------
__global__ __launch_bounds__(256) void k_gates_lstm(
    const float* __restrict__ xw, const float* __restrict__ h0,
    const float* __restrict__ c0, const float* __restrict__ wih,
    const float* __restrict__ bih, const float* __restrict__ whh,
    const float* __restrict__ bhh,
    float* __restrict__ h1o, float* __restrict__ c1o)
{
    int l = threadIdx.x & 63, g = threadIdx.x >> 6;
    int n = blockIdx.x;
    int b0 = blockIdx.y * 4;
    int j = g * 256 + n;
    __shared__ float gsum[4][4];

    float wi0 = wih[(size_t)j * 128 + l];
    float wi1 = wih[(size_t)j * 128 + l + 64];
    float wh[4];
    #pragma unroll
    for (int i = 0; i < 4; i++) wh[i] = whh[(size_t)j * 256 + l + 64 * i];
    float bj = bih[j] + bhh[j];

    #pragma unroll
    for (int bi = 0; bi < 4; bi++) {
        int b = b0 + bi;
        float a = xw[b * 128 + l] * wi0 + xw[b * 128 + l + 64] * wi1;
        #pragma unroll
        for (int i = 0; i < 4; i++) a += h0[b * 256 + l + 64 * i] * wh[i];
        a = wave_red(a);
        if (l == 0) gsum[g][bi] = a + bj;
    }
    __syncthreads();
    if (threadIdx.x < 4) {
        int b = b0 + threadIdx.x;
        float ig = sigf(gsum[0][threadIdx.x]);
        float fg = sigf(gsum[1][threadIdx.x]);
        float gg = tanh_fast(gsum[2][threadIdx.x]);
        float og = sigf(gsum[3][threadIdx.x]);
        float c1 = fg * c0[b * 256 + n] + ig * gg;
        float h1 = og * tanh_fast(c1);
        h1o[b * 256 + n] = h1;
        c1o[b * 256 + n] = c1;
    }
}

// ---------------------------------------------------------------------------
// K3: dec_fea[b,j] = [h1,c1]·Wp[j,:] + bp[j].  grid (512/4, B/4)
// ---------------------------------------------------------------------------
__global__ __launch_bounds__(256) void k_dec_fea(
    const float* __restrict__ h1, const float* __restrict__ c1,
    const float* __restrict__ Wp, const float* __restrict__ bp,
    float* __restrict__ dfw)
{
    int l = threadIdx.x & 63;
    int j = blockIdx.x * 4 + (threadIdx.x >> 6);
    int b0 = blockIdx.y * 4;
    float w[8];
    #pragma unroll
    for (int i = 0; i < 8; i++) w[i] = Wp[(size_t)j * 512 + l + 64 * i];
    float bj = bp[j];
    #pragma unroll
    for (int bi = 0; bi < 4; bi++) {
        int b = b0 + bi;
        float a = 0.f;
        #pragma unroll
        for (int i = 0; i < 4; i++) a += h1[b * 256 + l + 64 * i] * w[i];
        #pragma unroll
        for (int i = 0; i < 4; i++) a += c1[b * 256 + l + 64 * i] * w[4 + i];
        a = wave_red(a);
        if (l == 0) dfw[b * 512 + j] = a + bj;
    }
}

// ---------------------------------------------------------------------------
// K4: scores[b,t] — one wave per (b,t)
// ---------------------------------------------------------------------------
__global__ __launch_bounds__(256) void k_scores(
    const float* __restrict__ ef, const float* __restrict__ df,
    const float* __restrict__ cov, const float* __restrict__ Wc,
    const float* __restrict__ vw, float* __restrict__ sc)
{
    int w = threadIdx.x >> 6, lane = threadIdx.x & 63;
    int idx = blockIdx.x * 4 + w;
    int b = idx / TKk;
    const float* e = ef + (size_t)idx * N2n;
    const float* d = df + (size_t)b * N2n;
    float cv = cov[idx];
    float acc = 0.f;
    #pragma unroll
    for (int i = 0; i < 2; i++) {
        int n0 = lane * 4 + i * 256;
        float4 ev = *(const float4*)(e + n0);
        float4 dv = *(const float4*)(d + n0);
        float4 wc = *(const float4*)(Wc + n0);
        float4 vv = *(const float4*)(vw + n0);
        acc += tanh_fast(ev.x + dv.x + cv * wc.x) * vv.x;
        acc += tanh_fast(ev.y + dv.y + cv * wc.y) * vv.y;
        acc += tanh_fast(ev.z + dv.z + cv * wc.z) * vv.z;
        acc += tanh_fast(ev.w + dv.w + cv * wc.w) * vv.w;
    }
    acc = wave_red(acc);
    if (lane == 0) sc[idx] = acc;
}

// ---------------------------------------------------------------------------
// K5: masked softmax over TK + coverage update — one block per b
// ---------------------------------------------------------------------------
__global__ __launch_bounds__(512) void k_attn(
    const float* __restrict__ sc, const float* __restrict__ mask,
    const float* __restrict__ covi, float* __restrict__ attn,
    float* __restrict__ covo)
{
    int b = blockIdx.x, tid = threadIdx.x;
    __shared__ float red[8];
    __shared__ float bc;
    float s = (tid < TKk) ? sc[b * TKk + tid] : -3.4e38f;
    float m = s;
    for (int off = 32; off; off >>= 1) m = fmaxf(m, __shfl_down(m, off));
    if ((tid & 63) == 0) red[tid >> 6] = m;
    __syncthreads();
    if (tid == 0) {
        float t = red[0];
        for (int i = 1; i < 8; i++) t = fmaxf(t, red[i]);
        bc = t;
    }
    __syncthreads();
    float M = bc;
    float w = (tid < TKk) ? __expf(s - M) * mask[b * TKk + tid] : 0.f;
    float ss = wave_red(w);
    if ((tid & 63) == 0) red[tid >> 6] = ss;
    __syncthreads();
    if (tid == 0) {
        float t = 0.f;
        for (int i = 0; i < 8; i++) t += red[i];
        bc = t;
    }
    __syncthreads();
    float a = w / bc;
    if (tid < TKk) {
        attn[b * TKk + tid] = a;
        covo[b * TKk + tid] = covi[b * TKk + tid] + a;
    }
}

// ---------------------------------------------------------------------------
// K6: context partials over 100-key chunks
// ---------------------------------------------------------------------------
__global__ __launch_bounds__(512) void k_ctx(
    const float* __restrict__ attn, const float* __restrict__ eo,
    float* __restrict__ part)
{
    int bs = blockIdx.x;
    int b = bs >> 2, s = bs & 3;
    int n = threadIdx.x;
    __shared__ float av[100];
    if (n < 100) av[n] = attn[b * TKk + s * 100 + n];
    __syncthreads();
    const float* p = eo + ((size_t)b * TKk + s * 100) * N2n + n;
    float acc = 0.f;
    #pragma unroll 4
    for (int t = 0; t < 100; t++) acc += av[t] * p[(size_t)t * N2n];
    part[(size_t)bs * N2n + n] = acc;
}

// ---------------------------------------------------------------------------
// K7: c_t reduce + p_gen — one block per b
// ---------------------------------------------------------------------------
__global__ __launch_bounds__(512) void k_ctred(
    const float* __restrict__ part, const float* __restrict__ h1,
    const float* __restrict__ c1, const float* __restrict__ xw,
    const float* __restrict__ Wpg, const float* __restrict__ bpg,
    float* __restrict__ cto, float* __restrict__ pgo)
{
    int b = blockIdx.x, tid = threadIdx.x;
    __shared__ float ct[N2n];
    __shared__ float red[8];
    float a = part[((size_t)b * 4 + 0) * N2n + tid]
            + part[((size_t)b * 4 + 1) * N2n + tid]
            + part[((size_t)b * 4 + 2) * N2n + tid]
            + part[((size_t)b * 4 + 3) * N2n + tid];
    ct[tid] = a;
    cto[b * N2n + tid] = a;
    __syncthreads();

    float pa = 0.f;
    for (int k = tid; k < 1152; k += 512) {
        float vv = (k < 512) ? ct[k] : (k < 768) ? h1[b * 256 + k - 512]
                 : (k < 1024) ? c1[b * 256 + k - 768] : xw[b * 128 + k - 1024];
        pa += vv * Wpg[k];
    }
    pa = wave_red(pa);
    if ((tid & 63) == 0) red[tid >> 6] = pa;
    __syncthreads();
    if (tid == 0) {
        float t = 0.f;
        for (int i = 0; i < 8; i++) t += red[i];
        pgo[b] = sigf(t + bpg[0]);
    }
}

// ---------------------------------------------------------------------------
// K8: output[b,j] = [h1,c_t]·W1[j,:] + b1[j].  grid (256/4, B/4)
// ---------------------------------------------------------------------------
__global__ __launch_bounds__(256) void k_out(
    const float* __restrict__ h1, const float* __restrict__ cto,
    const float* __restrict__ W1, const float* __restrict__ b1,
    float* __restrict__ ov)
{
    int l = threadIdx.x & 63;
    int j = blockIdx.x * 4 + (threadIdx.x >> 6);
    int b0 = blockIdx.y * 4;
    float w[12];
    #pragma unroll
    for (int i = 0; i < 12; i++) w[i] = W1[(size_t)j * 768 + l + 64 * i];
    float bj = b1[j];
    #pragma unroll
    for (int bi = 0; bi < 4; bi++) {
        int b = b0 + bi;
        float a = 0.f;
        #pragma unroll
        for (int i = 0; i < 4; i++) a += h1[b * 256 + l + 64 * i] * w[i];
        #pragma unroll
        for (int i = 0; i < 8; i++) a += cto[b * 512 + l + 64 * i] * w[4 + i];
        a = wave_red(a);
        if (l == 0) ov[b * 256 + j] = a + bj;
    }
}

// ---------------------------------------------------------------------------
// K9: vocab GEMM: tile M=128 x N=64, Kc=16, micro 8x4
// ---------------------------------------------------------------------------
__global__ __launch_bounds__(256) void k_gemm(
    const float* __restrict__ Aw, const float* __restrict__ W2,
    const float* __restrict__ b2, float* __restrict__ fd)
{
    __shared__ float As[16 * 128];   // [k][m]
    __shared__ float Bs[16 * 64];    // [k][n]
    int tid = threadIdx.x;
    int tx = tid & 15;        // n = tx*4
    int ty = tid >> 4;        // m = ty*8
    int v0 = blockIdx.x * 64;
    int am = tid & 127, ah = tid >> 7;
    int bn = tid & 63,  bq = tid >> 6;

    float acc[8][4] = {};

    for (int kt = 0; kt < 256; kt += 16) {
        float4 a0 = *(const float4*)(Aw + (size_t)am * 256 + kt + ah * 8);
        float4 a1 = *(const float4*)(Aw + (size_t)am * 256 + kt + ah * 8 + 4);
        int vv = v0 + bn;
        float4 bv = make_float4(0.f, 0.f, 0.f, 0.f);
        if (vv < Vv) bv = *(const float4*)(W2 + (size_t)vv * 256 + kt + bq * 4);
        __syncthreads();
        As[(ah * 8 + 0) * 128 + am] = a0.x; As[(ah * 8 + 1) * 128 + am] = a0.y;
        As[(ah * 8 + 2) * 128 + am] = a0.z; As[(ah * 8 + 3) * 128 + am] = a0.w;
        As[(ah * 8 + 4) * 128 + am] = a1.x; As[(ah * 8 + 5) * 128 + am] = a1.y;
        As[(ah * 8 + 6) * 128 + am] = a1.z; As[(ah * 8 + 7) * 128 + am] = a1.w;
        Bs[(bq * 4 + 0) * 64 + bn] = bv.x; Bs[(bq * 4 + 1) * 64 + bn] = bv.y;
        Bs[(bq * 4 + 2) * 64 + bn] = bv.z; Bs[(bq * 4 + 3) * 64 + bn] = bv.w;
        __syncthreads();
        #pragma unroll
        for (int k = 0; k < 16; k++) {
            float4 A0 = *(const float4*)&As[k * 128 + ty * 8];
            float4 A1 = *(const float4*)&As[k * 128 + ty * 8 + 4];
            float4 Bv = *(const float4*)&Bs[k * 64 + tx * 4];
            float amv[8] = {A0.x, A0.y, A0.z, A0.w, A1.x, A1.y, A1.z, A1.w};
            float bnv[4] = {Bv.x, Bv.y, Bv.z, Bv.w};
            #pragma unroll
            for (int i = 0; i < 8; i++)
                #pragma unroll
                for (int j = 0; j < 4; j++) acc[i][j] += amv[i] * bnv[j];
        }
    }
    int v = v0 + tx * 4;
    if (v < Vv) {
        float4 bb = *(const float4*)(b2 + v);
        #pragma unroll
        for (int i = 0; i < 8; i++) {
            int m = ty * 8 + i;
            float* p = fd + (size_t)m * VOo + v;
            *(float2*)(p)     = make_float2(acc[i][0] + bb.x, acc[i][1] + bb.y);
            *(float2*)(p + 2) = make_float2(acc[i][2] + bb.z, acc[i][3] + bb.w);
        }
    }
}

// ---------------------------------------------------------------------------
// K10: vocab softmax partials per (b, quarter)
// ---------------------------------------------------------------------------
__global__ __launch_bounds__(256) void k_vs1(
    const float* __restrict__ fd, float* __restrict__ pm, float* __restrict__ ps)
{
    int blk = blockIdx.x, b = blk >> 2, c = blk & 3;
    int tid = threadIdx.x;
    const float* l = fd + (size_t)b * VOo + c * 12500;
    __shared__ float red[4];
    __shared__ float bc;
    float m = -3.4e38f;
    for (int v = tid; v < 12500; v += 256) m = fmaxf(m, l[v]);
    for (int off = 32; off; off >>= 1) m = fmaxf(m, __shfl_down(m, off));
    if ((tid & 63) == 0) red[tid >> 6] = m;
    __syncthreads();
    if (tid == 0) bc = fmaxf(fmaxf(red[0], red[1]), fmaxf(red[2], red[3]));
    __syncthreads();
    float M = bc;
    float s = 0.f;
    for (int v = tid; v < 12500; v += 256) s += __expf(l[v] - M);
    s = wave_red(s);
    if ((tid & 63) == 0) red[tid >> 6] = s;
    __syncthreads();
    if (tid == 0) { pm[blk] = M; ps[blk] = red[0] + red[1] + red[2] + red[3]; }
}

// ---------------------------------------------------------------------------
// K11: combine + normalize in place + p_gen scale + OOV tail
// ---------------------------------------------------------------------------
__global__ __launch_bounds__(256) void k_vs3(
    const float* __restrict__ pm, const float* __restrict__ ps,
    const float* __restrict__ pgen, const float* __restrict__ extra,
    float* __restrict__ fd)
{
    int blk = blockIdx.x, b = blk >> 2, c = blk & 3;
    float m0 = pm[b * 4], m1 = pm[b * 4 + 1], m2 = pm[b * 4 + 2], m3 = pm[b * 4 + 3];
    float M = fmaxf(fmaxf(m0, m1), fmaxf(m2, m3));
    float S = ps[b * 4] * __expf(m0 - M) + ps[b * 4 + 1] * __expf(m1 - M)
            + ps[b * 4 + 2] * __expf(m2 - M) + ps[b * 4 + 3] * __expf(m3 - M);
    float scale = pgen[b] / S;
    float* l = fd + (size_t)b * VOo + c * 12500;
    for (int v = threadIdx.x; v < 12500; v += 256) l[v] = __expf(l[v] - M) * scale;
    if (c == 0 && threadIdx.x < OOVn)
        fd[(size_t)b * VOo + Vv + threadIdx.x] = extra[b * OOVn + threadIdx.x];
}

// ---------------------------------------------------------------------------
// K12: pointer scatter-add
// ---------------------------------------------------------------------------
__global__ __launch_bounds__(256) void k_scatter(
    const int* __restrict__ ebev, const float* __restrict__ attn,
    const float* __restrict__ pgen, float* __restrict__ fd)
{
    int gid = blockIdx.x * 256 + threadIdx.x;
    if (gid >= Bb * TKk) return;
    int b = gid / TKk;
    float w = (1.f - pgen[b]) * attn[gid];
    atomicAdd(fd + (size_t)b * VOo + ebev[gid], w);
}

extern "C" void kernel_launch(void* const* d_in, const int* in_sizes, int n_in,
                              void* d_out, int out_size, void* d_ws, size_t ws_size,
                              hipStream_t stream)
{
    (void)in_sizes; (void)n_in; (void)out_size; (void)ws_size;

    const int*   y    = (const int*)d_in[0];
    const float* h0   = (const float*)d_in[1];
    const float* c0   = (const float*)d_in[2];
    const float* eo   = (const float*)d_in[3];
    const float* ef   = (const float*)d_in[4];
    const float* mask = (const float*)d_in[5];
    const float* ct1  = (const float*)d_in[6];
    const float* xz   = (const float*)d_in[7];
    const int*   ebev = (const int*)d_in[8];
    const float* cov  = (const float*)d_in[9];
    const float* emb  = (const float*)d_in[11];
    const float* Wx   = (const float*)d_in[12];
    const float* bx   = (const float*)d_in[13];
    const float* wih  = (const float*)d_in[14];
    const float* bih  = (const float*)d_in[15];
    const float* whh  = (const float*)d_in[16];
    const float* bhh  = (const float*)d_in[17];
    const float* Wp   = (const float*)d_in[18];
    const float* bp   = (const float*)d_in[19];
    const float* vw   = (const float*)d_in[20];
    const float* Wc   = (const float*)d_in[21];
    const float* Wpg  = (const float*)d_in[22];
    const float* bpg  = (const float*)d_in[23];
    const float* W1   = (const float*)d_in[24];
    const float* b1   = (const float*)d_in[25];
    const float* W2   = (const float*)d_in[26];
    const float* b2   = (const float*)d_in[27];

    float* out   = (float*)d_out;
    float* fd    = out;                              // [B, VO]
    float* h1o   = out + (size_t)Bb * VOo;           // [B, H]
    float* c1o   = h1o + (size_t)Bb * Hh;            // [B, H]
    float* cto   = c1o + (size_t)Bb * Hh;            // [B, N2]
    float* attno = cto + (size_t)Bb * N2n;           // [B, TK]
    float* pgo   = attno + (size_t)Bb * TKk;         // [B]
    float* covo  = pgo + Bb;                         // [B, TK]

    float* ws  = (float*)d_ws;
    float* xw  = ws;                                 // [B,128]
    float* dfw = xw + (size_t)Bb * EMB;              // [B,512]
    float* scw = dfw + (size_t)Bb * N2n;             // [B,400]
    float* prt = scw + (size_t)Bb * TKk;             // [B,4,512]
    float* ovw = prt + (size_t)Bb * 4 * N2n;         // [B,256]
    float* pmw = ovw + (size_t)Bb * Hh;              // [512]
    float* psw = pmw + 512;                          // [512]

    k_x<<<dim3(32, 32), 256, 0, stream>>>(y, ct1, emb, Wx, bx, xw);
    k_gates_lstm<<<dim3(256, 32), 256, 0, stream>>>(xw, h0, c0, wih, bih,
                                                    whh, bhh, h1o, c1o);
    k_dec_fea<<<dim3(128, 32), 256, 0, stream>>>(h1o, c1o, Wp, bp, dfw);
    k_scores<<<Bb * TKk / 4, 256, 0, stream>>>(ef, dfw, cov, Wc, vw, scw);
    k_attn<<<Bb, 512, 0, stream>>>(scw, mask, cov, attno, covo);
    k_ctx<<<Bb * 4, 512, 0, stream>>>(attno, eo, prt);
    k_ctred<<<Bb, 512, 0, stream>>>(prt, h1o, c1o, xw, Wpg, bpg, cto, pgo);
    k_out<<<dim3(64, 32), 256, 0, stream>>>(h1o, cto, W1, b1, ovw);
    k_gemm<<<(Vv + 63) / 64, 256, 0, stream>>>(ovw, W2, b2, fd);
    k_vs1<<<512, 256, 0, stream>>>(fd, pmw, psw);
    k_vs3<<<512, 256, 0, stream>>>(pmw, psw, pgo, xz, fd);
    k_scatter<<<(Bb * TKk + 255) / 256, 256, 0, stream>>>(ebev, attno, pgo, fd);
}

// Round 4
// 436.497 us; speedup vs baseline: 1.6283x; 1.0308x over previous
//
#include <hip/hip_runtime.h>
#include <math.h>

#define Vv   50000
#define EMB  128
#define Hh   256
#define TKk  400
#define Bb   128
#define OOVn 10
#define N2n  512
#define VOo  50010   // V + OOV

typedef __bf16 bf16x8 __attribute__((ext_vector_type(8)));
typedef float  f32x4  __attribute__((ext_vector_type(4)));

__device__ __forceinline__ float sigf(float x) { return 1.f / (1.f + __expf(-x)); }
__device__ __forceinline__ float tanh_fast(float x) {
    x = fminf(15.f, fmaxf(-15.f, x));
    float e = __expf(2.f * x);
    return (e - 1.f) / (e + 1.f);
}
__device__ __forceinline__ float wave_red(float v) {
    #pragma unroll
    for (int o = 32; o; o >>= 1) v += __shfl_down(v, o);
    return v;
}
// fp32 -> bf16 RNE
__device__ __forceinline__ unsigned short f2bf(float f) {
    unsigned u = __builtin_bit_cast(unsigned, f);
    unsigned r = u + 0x7fffu + ((u >> 16) & 1u);
    return (unsigned short)(r >> 16);
}

// ---------------------------------------------------------------------------
// K1: x[b,j] = concat(c_t_1, emb[y[b]]) . Wx[j,:] + bx[j]
// ---------------------------------------------------------------------------
__global__ __launch_bounds__(256) void k_x(
    const int* __restrict__ y, const float* __restrict__ ct1,
    const float* __restrict__ emb, const float* __restrict__ Wx,
    const float* __restrict__ bx, float* __restrict__ xw)
{
    int l = threadIdx.x & 63;
    int j = blockIdx.x * 4 + (threadIdx.x >> 6);
    int b0 = blockIdx.y * 4;
    float w[10];
    #pragma unroll
    for (int i = 0; i < 10; i++) w[i] = Wx[(size_t)j * 640 + l + 64 * i];
    float bj = bx[j];
    #pragma unroll
    for (int bi = 0; bi < 4; bi++) {
        int b = b0 + bi;
        int yy = y[b];
        float a = 0.f;
        #pragma unroll
        for (int i = 0; i < 8; i++) a += ct1[b * 512 + l + 64 * i] * w[i];
        #pragma unroll
        for (int i = 0; i < 2; i++) a += emb[(size_t)yy * 128 + l + 64 * i] * w[8 + i];
        a = wave_red(a);
        if (l == 0) xw[b * 128 + j] = a + bj;
    }
}

// ---------------------------------------------------------------------------
// K2: gates + LSTM fused
// ---------------------------------------------------------------------------
__global__ __launch_bounds__(256) void k_gates_lstm(
    const float* __restrict__ xw, const float* __restrict__ h0,
    const float* __restrict__ c0, const float* __restrict__ wih,
    const float* __restrict__ bih, const float* __restrict__ whh,
    const float* __restrict__ bhh,
    float* __restrict__ h1o, float* __restrict__ c1o)
{
    int l = threadIdx.x & 63, g = threadIdx.x >> 6;
    int n = blockIdx.x;
    int b0 = blockIdx.y * 4;
    int j = g * 256 + n;
    __shared__ float gsum[4][4];

    float wi0 = wih[(size_t)j * 128 + l];
    float wi1 = wih[(size_t)j * 128 + l + 64];
    float wh[4];
    #pragma unroll
    for (int i = 0; i < 4; i++) wh[i] = whh[(size_t)j * 256 + l + 64 * i];
    float bj = bih[j] + bhh[j];

    #pragma unroll
    for (int bi = 0; bi < 4; bi++) {
        int b = b0 + bi;
        float a = xw[b * 128 + l] * wi0 + xw[b * 128 + l + 64] * wi1;
        #pragma unroll
        for (int i = 0; i < 4; i++) a += h0[b * 256 + l + 64 * i] * wh[i];
        a = wave_red(a);
        if (l == 0) gsum[g][bi] = a + bj;
    }
    __syncthreads();
    if (threadIdx.x < 4) {
        int b = b0 + threadIdx.x;
        float ig = sigf(gsum[0][threadIdx.x]);
        float fg = sigf(gsum[1][threadIdx.x]);
        float gg = tanh_fast(gsum[2][threadIdx.x]);
        float og = sigf(gsum[3][threadIdx.x]);
        float c1 = fg * c0[b * 256 + n] + ig * gg;
        float h1 = og * tanh_fast(c1);
        h1o[b * 256 + n] = h1;
        c1o[b * 256 + n] = c1;
    }
}

// ---------------------------------------------------------------------------
// K3: dec_fea
// ---------------------------------------------------------------------------
__global__ __launch_bounds__(256) void k_dec_fea(
    const float* __restrict__ h1, const float* __restrict__ c1,
    const float* __restrict__ Wp, const float* __restrict__ bp,
    float* __restrict__ dfw)
{
    int l = threadIdx.x & 63;
    int j = blockIdx.x * 4 + (threadIdx.x >> 6);
    int b0 = blockIdx.y * 4;
    float w[8];
    #pragma unroll
    for (int i = 0; i < 8; i++) w[i] = Wp[(size_t)j * 512 + l + 64 * i];
    float bj = bp[j];
    #pragma unroll
    for (int bi = 0; bi < 4; bi++) {
        int b = b0 + bi;
        float a = 0.f;
        #pragma unroll
        for (int i = 0; i < 4; i++) a += h1[b * 256 + l + 64 * i] * w[i];
        #pragma unroll
        for (int i = 0; i < 4; i++) a += c1[b * 256 + l + 64 * i] * w[4 + i];
        a = wave_red(a);
        if (l == 0) dfw[b * 512 + j] = a + bj;
    }
}

// ---------------------------------------------------------------------------
// K4: scores
// ---------------------------------------------------------------------------
__global__ __launch_bounds__(256) void k_scores(
    const float* __restrict__ ef, const float* __restrict__ df,
    const float* __restrict__ cov, const float* __restrict__ Wc,
    const float* __restrict__ vw, float* __restrict__ sc)
{
    int w = threadIdx.x >> 6, lane = threadIdx.x & 63;
    int idx = blockIdx.x * 4 + w;
    int b = idx / TKk;
    const float* e = ef + (size_t)idx * N2n;
    const float* d = df + (size_t)b * N2n;
    float cv = cov[idx];
    float acc = 0.f;
    #pragma unroll
    for (int i = 0; i < 2; i++) {
        int n0 = lane * 4 + i * 256;
        float4 ev = *(const float4*)(e + n0);
        float4 dv = *(const float4*)(d + n0);
        float4 wc = *(const float4*)(Wc + n0);
        float4 vv = *(const float4*)(vw + n0);
        acc += tanh_fast(ev.x + dv.x + cv * wc.x) * vv.x;
        acc += tanh_fast(ev.y + dv.y + cv * wc.y) * vv.y;
        acc += tanh_fast(ev.z + dv.z + cv * wc.z) * vv.z;
        acc += tanh_fast(ev.w + dv.w + cv * wc.w) * vv.w;
    }
    acc = wave_red(acc);
    if (lane == 0) sc[idx] = acc;
}

// ---------------------------------------------------------------------------
// K5: masked softmax over TK + coverage
// ---------------------------------------------------------------------------
__global__ __launch_bounds__(512) void k_attn(
    const float* __restrict__ sc, const float* __restrict__ mask,
    const float* __restrict__ covi, float* __restrict__ attn,
    float* __restrict__ covo)
{
    int b = blockIdx.x, tid = threadIdx.x;
    __shared__ float red[8];
    __shared__ float bc;
    float s = (tid < TKk) ? sc[b * TKk + tid] : -3.4e38f;
    float m = s;
    for (int off = 32; off; off >>= 1) m = fmaxf(m, __shfl_down(m, off));
    if ((tid & 63) == 0) red[tid >> 6] = m;
    __syncthreads();
    if (tid == 0) {
        float t = red[0];
        for (int i = 1; i < 8; i++) t = fmaxf(t, red[i]);
        bc = t;
    }
    __syncthreads();
    float M = bc;
    float w = (tid < TKk) ? __expf(s - M) * mask[b * TKk + tid] : 0.f;
    float ss = wave_red(w);
    if ((tid & 63) == 0) red[tid >> 6] = ss;
    __syncthreads();
    if (tid == 0) {
        float t = 0.f;
        for (int i = 0; i < 8; i++) t += red[i];
        bc = t;
    }
    __syncthreads();
    float a = w / bc;
    if (tid < TKk) {
        attn[b * TKk + tid] = a;
        covo[b * TKk + tid] = covi[b * TKk + tid] + a;
    }
}

// ---------------------------------------------------------------------------
// K6: context partials
// ---------------------------------------------------------------------------
__global__ __launch_bounds__(512) void k_ctx(
    const float* __restrict__ attn, const float* __restrict__ eo,
    float* __restrict__ part)
{
    int bs = blockIdx.x;
    int b = bs >> 2, s = bs & 3;
    int n = threadIdx.x;
    __shared__ float av[100];
    if (n < 100) av[n] = attn[b * TKk + s * 100 + n];
    __syncthreads();
    const float* p = eo + ((size_t)b * TKk + s * 100) * N2n + n;
    float acc = 0.f;
    #pragma unroll 4
    for (int t = 0; t < 100; t++) acc += av[t] * p[(size_t)t * N2n];
    part[(size_t)bs * N2n + n] = acc;
}

// ---------------------------------------------------------------------------
// K7: c_t reduce + p_gen
// ---------------------------------------------------------------------------
__global__ __launch_bounds__(512) void k_ctred(
    const float* __restrict__ part, const float* __restrict__ h1,
    const float* __restrict__ c1, const float* __restrict__ xw,
    const float* __restrict__ Wpg, const float* __restrict__ bpg,
    float* __restrict__ cto, float* __restrict__ pgo)
{
    int b = blockIdx.x, tid = threadIdx.x;
    __shared__ float ct[N2n];
    __shared__ float red[8];
    float a = part[((size_t)b * 4 + 0) * N2n + tid]
            + part[((size_t)b * 4 + 1) * N2n + tid]
            + part[((size_t)b * 4 + 2) * N2n + tid]
            + part[((size_t)b * 4 + 3) * N2n + tid];
    ct[tid] = a;
    cto[b * N2n + tid] = a;
    __syncthreads();

    float pa = 0.f;
    for (int k = tid; k < 1152; k += 512) {
        float vv = (k < 512) ? ct[k] : (k < 768) ? h1[b * 256 + k - 512]
                 : (k < 1024) ? c1[b * 256 + k - 768] : xw[b * 128 + k - 1024];
        pa += vv * Wpg[k];
    }
    pa = wave_red(pa);
    if ((tid & 63) == 0) red[tid >> 6] = pa;
    __syncthreads();
    if (tid == 0) {
        float t = 0.f;
        for (int i = 0; i < 8; i++) t += red[i];
        pgo[b] = sigf(t + bpg[0]);
    }
}

// ---------------------------------------------------------------------------
// K8: output[b,j] = [h1,c_t]·W1[j,:] + b1[j] — writes bf16 for the MFMA GEMM
// ---------------------------------------------------------------------------
__global__ __launch_bounds__(256) void k_out(
    const float* __restrict__ h1, const float* __restrict__ cto,
    const float* __restrict__ W1, const float* __restrict__ b1,
    unsigned short* __restrict__ abf)
{
    int l = threadIdx.x & 63;
    int j = blockIdx.x * 4 + (threadIdx.x >> 6);
    int b0 = blockIdx.y * 4;
    float w[12];
    #pragma unroll
    for (int i = 0; i < 12; i++) w[i] = W1[(size_t)j * 768 + l + 64 * i];
    float bj = b1[j];
    #pragma unroll
    for (int bi = 0; bi < 4; bi++) {
        int b = b0 + bi;
        float a = 0.f;
        #pragma unroll
        for (int i = 0; i < 4; i++) a += h1[b * 256 + l + 64 * i] * w[i];
        #pragma unroll
        for (int i = 0; i < 8; i++) a += cto[b * 512 + l + 64 * i] * w[4 + i];
        a = wave_red(a);
        if (l == 0) abf[b * 256 + j] = f2bf(a + bj);
    }
}

// ---------------------------------------------------------------------------
// K9: MFMA bf16 vocab GEMM. logits[128, V] = A[128,256] @ W2^T + b2,
// written into fd rows (stride VOo). Block = 4 waves; wave w owns columns
// v0 + w*16 + (0..15), all 128 rows (8 m-tiles of 16). No LDS.
// A frags: 16B bf16 loads from abf. B frags: 2x float4 from W2, cvt->bf16.
// Layouts (m89/m120-verified): A[m=lane&15][k=quad*8+j],
// B[k=quad*8+j][n=lane&15], D: row=quad*4+reg, col=lane&15.
// ---------------------------------------------------------------------------
__global__ __launch_bounds__(256) void k_gemm_mfma(
    const unsigned short* __restrict__ abf, const float* __restrict__ W2,
    const float* __restrict__ b2, float* __restrict__ fd)
{
    int tid = threadIdx.x;
    int w = tid >> 6, lane = tid & 63;
    int ln = lane & 15, q = lane >> 4;
    int vcol = blockIdx.x * 64 + w * 16 + ln;
    bool valid = vcol < Vv;
    // clamp address in-bounds; garbage columns are never stored
    const float* bptr = W2 + (size_t)(valid ? vcol : 0) * 256 + q * 8;
    const unsigned short* aptr = abf + ln * 256 + q * 8;

    f32x4 acc[8] = {};

    #pragma unroll
    for (int kk = 0; kk < 256; kk += 32) {
        float4 bv0 = *(const float4*)(bptr + kk);
        float4 bv1 = *(const float4*)(bptr + kk + 4);
        unsigned short bu[8] = {
            f2bf(bv0.x), f2bf(bv0.y), f2bf(bv0.z), f2bf(bv0.w),
            f2bf(bv1.x), f2bf(bv1.y), f2bf(bv1.z), f2bf(bv1.w)};
        bf16x8 bfr = __builtin_bit_cast(bf16x8, *(const bf16x8*)bu);
        #pragma unroll
        for (int mt = 0; mt < 8; mt++) {
            bf16x8 afr = *(const bf16x8*)(aptr + (size_t)mt * 16 * 256 + kk);
            acc[mt] = __builtin_amdgcn_mfma_f32_16x16x32_bf16(afr, bfr, acc[mt], 0, 0, 0);
        }
    }

    if (valid) {
        float bias = b2[vcol];
        #pragma unroll
        for (int mt = 0; mt < 8; mt++) {
            #pragma unroll
            for (int r = 0; r < 4; r++) {
                int m = mt * 16 + q * 4 + r;
                fd[(size_t)m * VOo + vcol] = acc[mt][r] + bias;
            }
        }
    }
}

// ---------------------------------------------------------------------------
// K10: vocab softmax partials per (b, quarter)
// ---------------------------------------------------------------------------
__global__ __launch_bounds__(256) void k_vs1(
    const float* __restrict__ fd, float* __restrict__ pm, float* __restrict__ ps)
{
    int blk = blockIdx.x, b = blk >> 2, c = blk & 3;
    int tid = threadIdx.x;
    const float* l = fd + (size_t)b * VOo + c * 12500;
    __shared__ float red[4];
    __shared__ float bc;
    float m = -3.4e38f;
    for (int v = tid; v < 12500; v += 256) m = fmaxf(m, l[v]);
    for (int off = 32; off; off >>= 1) m = fmaxf(m, __shfl_down(m, off));
    if ((tid & 63) == 0) red[tid >> 6] = m;
    __syncthreads();
    if (tid == 0) bc = fmaxf(fmaxf(red[0], red[1]), fmaxf(red[2], red[3]));
    __syncthreads();
    float M = bc;
    float s = 0.f;
    for (int v = tid; v < 12500; v += 256) s += __expf(l[v] - M);
    s = wave_red(s);
    if ((tid & 63) == 0) red[tid >> 6] = s;
    __syncthreads();
    if (tid == 0) { pm[blk] = M; ps[blk] = red[0] + red[1] + red[2] + red[3]; }
}

// ---------------------------------------------------------------------------
// K11: combine + normalize in place + p_gen scale + OOV tail
// ---------------------------------------------------------------------------
__global__ __launch_bounds__(256) void k_vs3(
    const float* __restrict__ pm, const float* __restrict__ ps,
    const float* __restrict__ pgen, const float* __restrict__ extra,
    float* __restrict__ fd)
{
    int blk = blockIdx.x, b = blk >> 2, c = blk & 3;
    float m0 = pm[b * 4], m1 = pm[b * 4 + 1], m2 = pm[b * 4 + 2], m3 = pm[b * 4 + 3];
    float M = fmaxf(fmaxf(m0, m1), fmaxf(m2, m3));
    float S = ps[b * 4] * __expf(m0 - M) + ps[b * 4 + 1] * __expf(m1 - M)
            + ps[b * 4 + 2] * __expf(m2 - M) + ps[b * 4 + 3] * __expf(m3 - M);
    float scale = pgen[b] / S;
    float* l = fd + (size_t)b * VOo + c * 12500;
    for (int v = threadIdx.x; v < 12500; v += 256) l[v] = __expf(l[v] - M) * scale;
    if (c == 0 && threadIdx.x < OOVn)
        fd[(size_t)b * VOo + Vv + threadIdx.x] = extra[b * OOVn + threadIdx.x];
}

// ---------------------------------------------------------------------------
// K12: pointer scatter-add
// ---------------------------------------------------------------------------
__global__ __launch_bounds__(256) void k_scatter(
    const int* __restrict__ ebev, const float* __restrict__ attn,
    const float* __restrict__ pgen, float* __restrict__ fd)
{
    int gid = blockIdx.x * 256 + threadIdx.x;
    if (gid >= Bb * TKk) return;
    int b = gid / TKk;
    float w = (1.f - pgen[b]) * attn[gid];
    atomicAdd(fd + (size_t)b * VOo + ebev[gid], w);
}

extern "C" void kernel_launch(void* const* d_in, const int* in_sizes, int n_in,
                              void* d_out, int out_size, void* d_ws, size_t ws_size,
                              hipStream_t stream)
{
    (void)in_sizes; (void)n_in; (void)out_size; (void)ws_size;

    const int*   y    = (const int*)d_in[0];
    const float* h0   = (const float*)d_in[1];
    const float* c0   = (const float*)d_in[2];
    const float* eo   = (const float*)d_in[3];
    const float* ef   = (const float*)d_in[4];
    const float* mask = (const float*)d_in[5];
    const float* ct1  = (const float*)d_in[6];
    const float* xz   = (const float*)d_in[7];
    const int*   ebev = (const int*)d_in[8];
    const float* cov  = (const float*)d_in[9];
    const float* emb  = (const float*)d_in[11];
    const float* Wx   = (const float*)d_in[12];
    const float* bx   = (const float*)d_in[13];
    const float* wih  = (const float*)d_in[14];
    const float* bih  = (const float*)d_in[15];
    const float* whh  = (const float*)d_in[16];
    const float* bhh  = (const float*)d_in[17];
    const float* Wp   = (const float*)d_in[18];
    const float* bp   = (const float*)d_in[19];
    const float* vw   = (const float*)d_in[20];
    const float* Wc   = (const float*)d_in[21];
    const float* Wpg  = (const float*)d_in[22];
    const float* bpg  = (const float*)d_in[23];
    const float* W1   = (const float*)d_in[24];
    const float* b1   = (const float*)d_in[25];
    const float* W2   = (const float*)d_in[26];
    const float* b2   = (const float*)d_in[27];

    float* out   = (float*)d_out;
    float* fd    = out;                              // [B, VO]
    float* h1o   = out + (size_t)Bb * VOo;           // [B, H]
    float* c1o   = h1o + (size_t)Bb * Hh;            // [B, H]
    float* cto   = c1o + (size_t)Bb * Hh;            // [B, N2]
    float* attno = cto + (size_t)Bb * N2n;           // [B, TK]
    float* pgo   = attno + (size_t)Bb * TKk;         // [B]
    float* covo  = pgo + Bb;                         // [B, TK]

    float* ws  = (float*)d_ws;
    float* xw  = ws;                                 // [B,128]
    float* dfw = xw + (size_t)Bb * EMB;              // [B,512]
    float* scw = dfw + (size_t)Bb * N2n;             // [B,400]
    float* prt = scw + (size_t)Bb * TKk;             // [B,4,512]
    float* pmw = prt + (size_t)Bb * 4 * N2n;         // [512]
    float* psw = pmw + 512;                          // [512]
    unsigned short* abf = (unsigned short*)(psw + 512); // [B,256] bf16 (16B-aligned)

    k_x<<<dim3(32, 32), 256, 0, stream>>>(y, ct1, emb, Wx, bx, xw);
    k_gates_lstm<<<dim3(256, 32), 256, 0, stream>>>(xw, h0, c0, wih, bih,
                                                    whh, bhh, h1o, c1o);
    k_dec_fea<<<dim3(128, 32), 256, 0, stream>>>(h1o, c1o, Wp, bp, dfw);
    k_scores<<<Bb * TKk / 4, 256, 0, stream>>>(ef, dfw, cov, Wc, vw, scw);
    k_attn<<<Bb, 512, 0, stream>>>(scw, mask, cov, attno, covo);
    k_ctx<<<Bb * 4, 512, 0, stream>>>(attno, eo, prt);
    k_ctred<<<Bb, 512, 0, stream>>>(prt, h1o, c1o, xw, Wpg, bpg, cto, pgo);
    k_out<<<dim3(64, 32), 256, 0, stream>>>(h1o, cto, W1, b1, abf);
    k_gemm_mfma<<<(Vv + 63) / 64, 256, 0, stream>>>(abf, W2, b2, fd);
    k_vs1<<<512, 256, 0, stream>>>(fd, pmw, psw);
    k_vs3<<<512, 256, 0, stream>>>(pmw, psw, pgo, xz, fd);
    k_scatter<<<(Bb * TKk + 255) / 256, 256, 0, stream>>>(ebev, attno, pgo, fd);
}